// Round 1
// baseline (478.009 us; speedup 1.0000x reference)
//
#include <hip/hip_runtime.h>
#include <hip/hip_bf16.h>

typedef __attribute__((ext_vector_type(8))) short short8;
typedef __attribute__((ext_vector_type(4))) float f32x4;

#define N_NODES 16384
#define FEAT 128

__device__ __forceinline__ short f2bf(float x) {
  union { float f; unsigned u; } v;
  v.f = x;
  unsigned r = v.u + 0x7fffu + ((v.u >> 16) & 1u);  // RNE; inputs finite
  return (short)(r >> 16);
}

// ---------- Kernel 1: dinv[i] = rsqrt(1 + sum_j adj[i][j]) ----------
__global__ __launch_bounds__(256) void rowsum_kernel(
    const float* __restrict__ adj, float* __restrict__ dinv)
{
  const int row = blockIdx.x;
  const float4* p4 = (const float4*)(adj + (size_t)row * N_NODES);
  float s = 0.f;
  #pragma unroll 4
  for (int i = threadIdx.x; i < N_NODES / 4; i += 256) {
    float4 v = p4[i];
    s += (v.x + v.y) + (v.z + v.w);
  }
  #pragma unroll
  for (int off = 32; off > 0; off >>= 1) s += __shfl_down(s, off, 64);
  __shared__ float part[4];
  if ((threadIdx.x & 63) == 0) part[threadIdx.x >> 6] = s;
  __syncthreads();
  if (threadIdx.x == 0) {
    float tot = (part[0] + part[1]) + (part[2] + part[3]) + 1.0f;
    dinv[row] = rsqrtf(tot);
  }
}

// ---------- Kernel 2: Y[j][f] = d_j * (X@W)[j][f], bf16, natural + transposed ----------
__global__ __launch_bounds__(256) void xw_kernel(
    const float* __restrict__ X, const float* __restrict__ W,
    const float* __restrict__ dinv,
    __hip_bfloat16* __restrict__ Ynat, __hip_bfloat16* __restrict__ Ytg)
{
  __shared__ __align__(16) float Ws[64][128];   // 32 KiB (W staged in 2 chunks of 64 rows)
  __shared__ __align__(16) float Xs[32][128];   // 16 KiB
  __shared__ __align__(16) short Ts[128][40];   // 10 KiB transpose buffer (pad->40)
  const int tid = threadIdx.x;
  const int row0 = blockIdx.x << 5;             // 32 rows per block

  {
    const float4* Xg = (const float4*)(X + ((size_t)row0 << 7));
    float4* Xl = (float4*)&Xs[0][0];
    #pragma unroll
    for (int i = 0; i < 4; ++i) Xl[tid + (i << 8)] = Xg[tid + (i << 8)];
  }
  const int f  = tid & 127;
  const int rr = tid >> 7;                      // 0/1: rows rr, rr+2, ... rr+30
  float acc[16];
  #pragma unroll
  for (int k = 0; k < 16; ++k) acc[k] = 0.f;

  for (int cc = 0; cc < 2; ++cc) {
    __syncthreads();                            // Xs ready (cc=0); Ws free (cc=1)
    {
      const float4* Wg = (const float4*)(W + ((size_t)cc << 13));
      float4* Wl = (float4*)&Ws[0][0];
      #pragma unroll
      for (int i = 0; i < 8; ++i) Wl[tid + (i << 8)] = Wg[tid + (i << 8)];
    }
    __syncthreads();
    for (int c4 = 0; c4 < 16; ++c4) {
      const int cl = c4 << 2;
      const float w0 = Ws[cl + 0][f];
      const float w1 = Ws[cl + 1][f];
      const float w2 = Ws[cl + 2][f];
      const float w3 = Ws[cl + 3][f];
      const int cg = (cc << 6) + cl;
      #pragma unroll
      for (int k = 0; k < 16; ++k) {
        const float4 x = *(const float4*)&Xs[rr + (k << 1)][cg];
        acc[k] += x.x * w0 + x.y * w1 + x.z * w2 + x.w * w3;
      }
    }
  }
  #pragma unroll
  for (int k = 0; k < 16; ++k) {
    const int r = rr + (k << 1);
    const float dv = dinv[row0 + r];
    const short v = f2bf(acc[k] * dv);
    ((short*)Ynat)[(size_t)(row0 + r) * FEAT + f] = v;
    Ts[f][r] = v;
  }
  __syncthreads();
  {
    const int f2 = tid >> 1;
    const int h  = (tid & 1) << 4;
    const short8 v0 = *(const short8*)&Ts[f2][h];
    const short8 v1 = *(const short8*)&Ts[f2][h + 8];
    short* o = (short*)Ytg + (size_t)f2 * N_NODES + row0 + h;
    *(short8*)(o)     = v0;
    *(short8*)(o + 8) = v1;
  }
}

// ---------- Kernel 3: out = relu(d_i*((A@Y)[i] + Y[i]) + b), bf16 MFMA ----------
// BM=64, BK=64, 512 thr (8 waves: wm 0..3 x wf 0..1), double-buffered LDS.
__global__ __launch_bounds__(512) void spmm_kernel(
    const float* __restrict__ A,
    const __hip_bfloat16* __restrict__ Ynat,
    const __hip_bfloat16* __restrict__ Ytg,
    const float* __restrict__ dinv,
    const float* __restrict__ bias,
    float* __restrict__ out)
{
  __shared__ __align__(16) short As[2][64][72];    // 18 KiB (pad 64->72: 8-slot optimal)
  __shared__ __align__(16) short Bs[2][128][72];   // 36 KiB
  const int tid  = threadIdx.x;
  const int row0 = blockIdx.x << 6;

  // A staging: thread -> (row ar, k-chunk ak of 8 floats)
  const int ar = tid >> 3;
  const int ak = (tid & 7) << 3;
  const float* Ag = A + (size_t)(row0 + ar) * N_NODES + ak;
  // Y staging: thread -> (feature row yf, k-chunk yk of 16 bf16)
  const int yf = tid >> 2;
  const int yk = (tid & 3) << 4;
  const short* Yg = (const short*)Ytg + (size_t)yf * N_NODES + yk;

  const int wid  = tid >> 6;
  const int wm   = wid >> 1;        // 0..3: M-tile (16 rows)
  const int wf   = wid & 1;         // 0..1: F-half (64 cols)
  const int lane = tid & 63;
  const int lm   = lane & 15;
  const int lk   = (lane >> 4) << 3;

  f32x4 acc[4];
  #pragma unroll
  for (int c = 0; c < 4; ++c) acc[c] = (f32x4){0.f, 0.f, 0.f, 0.f};

  // prologue: stage tile 0
  {
    const float4 a0 = *(const float4*)(Ag);
    const float4 a1 = *(const float4*)(Ag + 4);
    const short8 y0 = *(const short8*)(Yg);
    const short8 y1 = *(const short8*)(Yg + 8);
    short8 ac;
    ac[0] = f2bf(a0.x); ac[1] = f2bf(a0.y); ac[2] = f2bf(a0.z); ac[3] = f2bf(a0.w);
    ac[4] = f2bf(a1.x); ac[5] = f2bf(a1.y); ac[6] = f2bf(a1.z); ac[7] = f2bf(a1.w);
    *(short8*)&As[0][ar][ak]     = ac;
    *(short8*)&Bs[0][yf][yk]     = y0;
    *(short8*)&Bs[0][yf][yk + 8] = y1;
  }
  __syncthreads();

  int p = 0;
  for (int t = 0; t < N_NODES / 64; ++t) {
    float4 a0, a1; short8 y0, y1;
    const bool pre = (t + 1) < (N_NODES / 64);
    if (pre) {                        // prefetch tile t+1 (covers HBM latency under compute)
      const float* Ab = Ag + ((size_t)(t + 1) << 6);
      a0 = *(const float4*)(Ab);
      a1 = *(const float4*)(Ab + 4);
      const short* Yb = Yg + ((t + 1) << 6);
      y0 = *(const short8*)(Yb);
      y1 = *(const short8*)(Yb + 8);
    }
    // compute tile t from buffer p
    #pragma unroll
    for (int ks = 0; ks < 2; ++ks) {
      const short8 af = *(const short8*)&As[p][(wm << 4) + lm][(ks << 5) + lk];
      #pragma unroll
      for (int c = 0; c < 4; ++c) {
        const short8 bf = *(const short8*)&Bs[p][(wf << 6) + (c << 4) + lm][(ks << 5) + lk];
        acc[c] = __builtin_amdgcn_mfma_f32_16x16x32_bf16(af, bf, acc[c], 0, 0, 0);
      }
    }
    if (pre) {                        // stage tile t+1 into buffer p^1
      short8 ac;
      ac[0] = f2bf(a0.x); ac[1] = f2bf(a0.y); ac[2] = f2bf(a0.z); ac[3] = f2bf(a0.w);
      ac[4] = f2bf(a1.x); ac[5] = f2bf(a1.y); ac[6] = f2bf(a1.z); ac[7] = f2bf(a1.w);
      *(short8*)&As[p ^ 1][ar][ak]     = ac;
      *(short8*)&Bs[p ^ 1][yf][yk]     = y0;
      *(short8*)&Bs[p ^ 1][yf][yk + 8] = y1;
    }
    __syncthreads();
    p ^= 1;
  }

  // epilogue: out[row][col] = relu(d_row * (acc + Y[row][col]) + b[col])
  const int lr = (lane >> 4) << 2;
  float dreg[4];
  #pragma unroll
  for (int r = 0; r < 4; ++r) dreg[r] = dinv[row0 + (wm << 4) + lr + r];
  #pragma unroll
  for (int c = 0; c < 4; ++c) {
    const int col = (wf << 6) + (c << 4) + lm;
    const float bv = bias[col];
    #pragma unroll
    for (int r = 0; r < 4; ++r) {
      const int row = row0 + (wm << 4) + lr + r;
      const float y = __bfloat162float(Ynat[(size_t)row * FEAT + col]);
      const float v = dreg[r] * (acc[c][r] + y) + bv;
      out[(size_t)row * FEAT + col] = v > 0.f ? v : 0.f;
    }
  }
}

extern "C" void kernel_launch(void* const* d_in, const int* in_sizes, int n_in,
                              void* d_out, int out_size, void* d_ws, size_t ws_size,
                              hipStream_t stream) {
  const float* X   = (const float*)d_in[0];
  const float* adj = (const float*)d_in[1];
  const float* W   = (const float*)d_in[2];
  const float* b   = (const float*)d_in[3];
  float* out = (float*)d_out;

  float* dinv = (float*)d_ws;                                              // 64 KiB
  __hip_bfloat16* Ynat = (__hip_bfloat16*)((char*)d_ws + (1 << 16));       // 4 MiB
  __hip_bfloat16* Ytg  = (__hip_bfloat16*)((char*)d_ws + (1 << 16) + (1 << 22)); // 4 MiB

  rowsum_kernel<<<N_NODES, 256, 0, stream>>>(adj, dinv);
  xw_kernel<<<N_NODES / 32, 256, 0, stream>>>(X, W, dinv, Ynat, Ytg);
  spmm_kernel<<<N_NODES / 64, 512, 0, stream>>>(adj, Ynat, Ytg, dinv, b, out);
}